// Round 6
// baseline (12682.220 us; speedup 1.0000x reference)
//
#include <hip/hip_runtime.h>

typedef __attribute__((ext_vector_type(8))) short short8;
typedef __attribute__((ext_vector_type(4))) float f32x4;
typedef __attribute__((ext_vector_type(4))) unsigned short u16x4;
typedef unsigned short ushort;
typedef unsigned long long ull;

#define MFMA16(a,b,c) __builtin_amdgcn_mfma_f32_16x16x32_bf16((a),(b),(c),0,0,0)

static __device__ __forceinline__ float bf2f(ushort u){
  union { unsigned int i; float f; } z; z.i = ((unsigned int)u) << 16; return z.f;
}
static __device__ __forceinline__ ushort f2bf(float f){
  union { float f; unsigned int i; } z; z.f = f;
  unsigned int x = z.i;
  unsigned int r = (x + 0x7fffu + ((x >> 16) & 1u)) >> 16;   // RNE
  return (ushort)r;
}

// 16B coherence-point load (2x u64 agent atomics) -- proven-correct path
static __device__ __forceinline__ short8 ld_hc16(const ushort* p){
  union { ull q[2]; short8 v; } u;
  u.q[0] = __hip_atomic_load((const ull*)p, __ATOMIC_RELAXED, __HIP_MEMORY_SCOPE_AGENT);
  u.q[1] = __hip_atomic_load((const ull*)(p + 4), __ATOMIC_RELAXED, __HIP_MEMORY_SCOPE_AGENT);
  return u.v;
}
// single bf16 from ring via aligned u32 agent atomic (proven)
static __device__ __forceinline__ float ld_ring_bf(const ushort* base, int idx){
  const unsigned int* p = (const unsigned int*)(base + (idx & ~1));
  unsigned int w = __hip_atomic_load(p, __ATOMIC_RELAXED, __HIP_MEMORY_SCOPE_AGENT);
  return bf2f((idx & 1) ? (ushort)(w >> 16) : (ushort)(w & 0xffffu));
}
// 2B / 8B write-through stores to coherence point (proven)
static __device__ __forceinline__ void st_hc2(ushort* p, ushort v){
  unsigned int vv = v;
  asm volatile("global_store_short %0, %1, off sc0 sc1" :: "v"(p), "v"(vv) : "memory");
}
static __device__ __forceinline__ void st_hc8(ushort* p, ull v){
  asm volatile("global_store_dwordx2 %0, %1, off sc0 sc1" :: "v"(p), "v"(v) : "memory");
}

// ---- batched 16-fragment system-scope load, wait INSIDE the asm (proven r5).
static __device__ __forceinline__ void ld_frag16(const ushort* p, short8* o){
  asm volatile(
    "global_load_dwordx4 %0, %16, off sc0 sc1\n\t"
    "global_load_dwordx4 %1, %16, off offset:64 sc0 sc1\n\t"
    "global_load_dwordx4 %2, %16, off offset:128 sc0 sc1\n\t"
    "global_load_dwordx4 %3, %16, off offset:192 sc0 sc1\n\t"
    "global_load_dwordx4 %4, %16, off offset:256 sc0 sc1\n\t"
    "global_load_dwordx4 %5, %16, off offset:320 sc0 sc1\n\t"
    "global_load_dwordx4 %6, %16, off offset:384 sc0 sc1\n\t"
    "global_load_dwordx4 %7, %16, off offset:448 sc0 sc1\n\t"
    "global_load_dwordx4 %8, %16, off offset:512 sc0 sc1\n\t"
    "global_load_dwordx4 %9, %16, off offset:576 sc0 sc1\n\t"
    "global_load_dwordx4 %10, %16, off offset:640 sc0 sc1\n\t"
    "global_load_dwordx4 %11, %16, off offset:704 sc0 sc1\n\t"
    "global_load_dwordx4 %12, %16, off offset:768 sc0 sc1\n\t"
    "global_load_dwordx4 %13, %16, off offset:832 sc0 sc1\n\t"
    "global_load_dwordx4 %14, %16, off offset:896 sc0 sc1\n\t"
    "global_load_dwordx4 %15, %16, off offset:960 sc0 sc1\n\t"
    "s_waitcnt vmcnt(0)"
    : "=&v"(o[0]), "=&v"(o[1]), "=&v"(o[2]), "=&v"(o[3]),
      "=&v"(o[4]), "=&v"(o[5]), "=&v"(o[6]), "=&v"(o[7]),
      "=&v"(o[8]), "=&v"(o[9]), "=&v"(o[10]), "=&v"(o[11]),
      "=&v"(o[12]), "=&v"(o[13]), "=&v"(o[14]), "=&v"(o[15])
    : "v"(p)
    : "memory");
  __builtin_amdgcn_sched_barrier(0);
}

// ---- dual-base 32-fragment batched load: avx (base pa) + avm (base pb) in
// ONE in-flight batch, single wait -> 1 L3 round-trip instead of 2.
static __device__ __forceinline__ void ld_frag32(const ushort* pa, const ushort* pb,
                                                 short8* oa, short8* ob){
  asm volatile(
    "global_load_dwordx4 %0, %32, off sc0 sc1\n\t"
    "global_load_dwordx4 %1, %32, off offset:64 sc0 sc1\n\t"
    "global_load_dwordx4 %2, %32, off offset:128 sc0 sc1\n\t"
    "global_load_dwordx4 %3, %32, off offset:192 sc0 sc1\n\t"
    "global_load_dwordx4 %4, %32, off offset:256 sc0 sc1\n\t"
    "global_load_dwordx4 %5, %32, off offset:320 sc0 sc1\n\t"
    "global_load_dwordx4 %6, %32, off offset:384 sc0 sc1\n\t"
    "global_load_dwordx4 %7, %32, off offset:448 sc0 sc1\n\t"
    "global_load_dwordx4 %8, %32, off offset:512 sc0 sc1\n\t"
    "global_load_dwordx4 %9, %32, off offset:576 sc0 sc1\n\t"
    "global_load_dwordx4 %10, %32, off offset:640 sc0 sc1\n\t"
    "global_load_dwordx4 %11, %32, off offset:704 sc0 sc1\n\t"
    "global_load_dwordx4 %12, %32, off offset:768 sc0 sc1\n\t"
    "global_load_dwordx4 %13, %32, off offset:832 sc0 sc1\n\t"
    "global_load_dwordx4 %14, %32, off offset:896 sc0 sc1\n\t"
    "global_load_dwordx4 %15, %32, off offset:960 sc0 sc1\n\t"
    "global_load_dwordx4 %16, %33, off sc0 sc1\n\t"
    "global_load_dwordx4 %17, %33, off offset:64 sc0 sc1\n\t"
    "global_load_dwordx4 %18, %33, off offset:128 sc0 sc1\n\t"
    "global_load_dwordx4 %19, %33, off offset:192 sc0 sc1\n\t"
    "global_load_dwordx4 %20, %33, off offset:256 sc0 sc1\n\t"
    "global_load_dwordx4 %21, %33, off offset:320 sc0 sc1\n\t"
    "global_load_dwordx4 %22, %33, off offset:384 sc0 sc1\n\t"
    "global_load_dwordx4 %23, %33, off offset:448 sc0 sc1\n\t"
    "global_load_dwordx4 %24, %33, off offset:512 sc0 sc1\n\t"
    "global_load_dwordx4 %25, %33, off offset:576 sc0 sc1\n\t"
    "global_load_dwordx4 %26, %33, off offset:640 sc0 sc1\n\t"
    "global_load_dwordx4 %27, %33, off offset:704 sc0 sc1\n\t"
    "global_load_dwordx4 %28, %33, off offset:768 sc0 sc1\n\t"
    "global_load_dwordx4 %29, %33, off offset:832 sc0 sc1\n\t"
    "global_load_dwordx4 %30, %33, off offset:896 sc0 sc1\n\t"
    "global_load_dwordx4 %31, %33, off offset:960 sc0 sc1\n\t"
    "s_waitcnt vmcnt(0)"
    : "=&v"(oa[0]), "=&v"(oa[1]), "=&v"(oa[2]), "=&v"(oa[3]),
      "=&v"(oa[4]), "=&v"(oa[5]), "=&v"(oa[6]), "=&v"(oa[7]),
      "=&v"(oa[8]), "=&v"(oa[9]), "=&v"(oa[10]), "=&v"(oa[11]),
      "=&v"(oa[12]), "=&v"(oa[13]), "=&v"(oa[14]), "=&v"(oa[15]),
      "=&v"(ob[0]), "=&v"(ob[1]), "=&v"(ob[2]), "=&v"(ob[3]),
      "=&v"(ob[4]), "=&v"(ob[5]), "=&v"(ob[6]), "=&v"(ob[7]),
      "=&v"(ob[8]), "=&v"(ob[9]), "=&v"(ob[10]), "=&v"(ob[11]),
      "=&v"(ob[12]), "=&v"(ob[13]), "=&v"(ob[14]), "=&v"(ob[15])
    : "v"(pa), "v"(pb)
    : "memory");
  __builtin_amdgcn_sched_barrier(0);
}

// ---- role2 variant: 32 fragments + 6 scalar ring words, all in one batch.
static __device__ __forceinline__ void ld_frag32s(
    const ushort* pa, const ushort* pb,
    const ushort* q0, const ushort* q1, const ushort* q2,
    const ushort* q3, const ushort* q4, const ushort* q5,
    short8* oa, short8* ob,
    unsigned int* s0, unsigned int* s1, ull* s2,
    unsigned int* s3, unsigned int* s4, ull* s5)
{
  asm volatile(
    "global_load_dwordx4 %0, %38, off sc0 sc1\n\t"
    "global_load_dwordx4 %1, %38, off offset:64 sc0 sc1\n\t"
    "global_load_dwordx4 %2, %38, off offset:128 sc0 sc1\n\t"
    "global_load_dwordx4 %3, %38, off offset:192 sc0 sc1\n\t"
    "global_load_dwordx4 %4, %38, off offset:256 sc0 sc1\n\t"
    "global_load_dwordx4 %5, %38, off offset:320 sc0 sc1\n\t"
    "global_load_dwordx4 %6, %38, off offset:384 sc0 sc1\n\t"
    "global_load_dwordx4 %7, %38, off offset:448 sc0 sc1\n\t"
    "global_load_dwordx4 %8, %38, off offset:512 sc0 sc1\n\t"
    "global_load_dwordx4 %9, %38, off offset:576 sc0 sc1\n\t"
    "global_load_dwordx4 %10, %38, off offset:640 sc0 sc1\n\t"
    "global_load_dwordx4 %11, %38, off offset:704 sc0 sc1\n\t"
    "global_load_dwordx4 %12, %38, off offset:768 sc0 sc1\n\t"
    "global_load_dwordx4 %13, %38, off offset:832 sc0 sc1\n\t"
    "global_load_dwordx4 %14, %38, off offset:896 sc0 sc1\n\t"
    "global_load_dwordx4 %15, %38, off offset:960 sc0 sc1\n\t"
    "global_load_dwordx4 %16, %39, off sc0 sc1\n\t"
    "global_load_dwordx4 %17, %39, off offset:64 sc0 sc1\n\t"
    "global_load_dwordx4 %18, %39, off offset:128 sc0 sc1\n\t"
    "global_load_dwordx4 %19, %39, off offset:192 sc0 sc1\n\t"
    "global_load_dwordx4 %20, %39, off offset:256 sc0 sc1\n\t"
    "global_load_dwordx4 %21, %39, off offset:320 sc0 sc1\n\t"
    "global_load_dwordx4 %22, %39, off offset:384 sc0 sc1\n\t"
    "global_load_dwordx4 %23, %39, off offset:448 sc0 sc1\n\t"
    "global_load_dwordx4 %24, %39, off offset:512 sc0 sc1\n\t"
    "global_load_dwordx4 %25, %39, off offset:576 sc0 sc1\n\t"
    "global_load_dwordx4 %26, %39, off offset:640 sc0 sc1\n\t"
    "global_load_dwordx4 %27, %39, off offset:704 sc0 sc1\n\t"
    "global_load_dwordx4 %28, %39, off offset:768 sc0 sc1\n\t"
    "global_load_dwordx4 %29, %39, off offset:832 sc0 sc1\n\t"
    "global_load_dwordx4 %30, %39, off offset:896 sc0 sc1\n\t"
    "global_load_dwordx4 %31, %39, off offset:960 sc0 sc1\n\t"
    "global_load_dword %32, %40, off sc0 sc1\n\t"
    "global_load_dword %33, %41, off sc0 sc1\n\t"
    "global_load_dwordx2 %34, %42, off sc0 sc1\n\t"
    "global_load_dword %35, %43, off sc0 sc1\n\t"
    "global_load_dword %36, %44, off sc0 sc1\n\t"
    "global_load_dwordx2 %37, %45, off sc0 sc1\n\t"
    "s_waitcnt vmcnt(0)"
    : "=&v"(oa[0]), "=&v"(oa[1]), "=&v"(oa[2]), "=&v"(oa[3]),
      "=&v"(oa[4]), "=&v"(oa[5]), "=&v"(oa[6]), "=&v"(oa[7]),
      "=&v"(oa[8]), "=&v"(oa[9]), "=&v"(oa[10]), "=&v"(oa[11]),
      "=&v"(oa[12]), "=&v"(oa[13]), "=&v"(oa[14]), "=&v"(oa[15]),
      "=&v"(ob[0]), "=&v"(ob[1]), "=&v"(ob[2]), "=&v"(ob[3]),
      "=&v"(ob[4]), "=&v"(ob[5]), "=&v"(ob[6]), "=&v"(ob[7]),
      "=&v"(ob[8]), "=&v"(ob[9]), "=&v"(ob[10]), "=&v"(ob[11]),
      "=&v"(ob[12]), "=&v"(ob[13]), "=&v"(ob[14]), "=&v"(ob[15]),
      "=&v"(*s0), "=&v"(*s1), "=&v"(*s2), "=&v"(*s3), "=&v"(*s4), "=&v"(*s5)
    : "v"(pa), "v"(pb), "v"(q0), "v"(q1), "v"(q2), "v"(q3), "v"(q4), "v"(q5)
    : "memory");
  __builtin_amdgcn_sched_barrier(0);
}

// ---------------------------------------------------------------------------
// fp32 -> bf16 convert, 4 elems/thread
// ---------------------------------------------------------------------------
__global__ __launch_bounds__(256) void cvt_k(
    const float* __restrict__ in, ushort* __restrict__ out, int n)
{
  int i = (blockIdx.x * 256 + threadIdx.x) * 4;
  if (i < n){
    float4 v = *(const float4*)(in + i);
    u16x4 o = { f2bf(v.x), f2bf(v.y), f2bf(v.z), f2bf(v.w) };
    *(u16x4*)(out + i) = o;
  }
}

// ---------------------------------------------------------------------------
// GEMM: C[M,N] = A[M,K](bf16) @ B[K,N](bf16) + bias[N](fp32).
// ---------------------------------------------------------------------------
template<int F32OUT>
__global__ __launch_bounds__(256) void gemm_bias_k(
    const ushort* __restrict__ A,
    const ushort* __restrict__ B,
    const float*  __restrict__ bias,
    void* __restrict__ Cv,
    int M, int N, int K)
{
  __shared__ __align__(16) ushort Blds[64 * 40];
  const int tid  = threadIdx.x;
  const int wid  = tid >> 6;
  const int lane = tid & 63;
  const int quad = lane >> 4;
  const int lc   = lane & 15;
  const int nb   = N >> 6;
  const int bn   = (blockIdx.x % nb) << 6;
  const int bm   = (blockIdx.x / nb) << 6;

  const int sk  = tid >> 3;
  const int scg = tid & 7;

  f32x4 acc[4] = {{0,0,0,0},{0,0,0,0},{0,0,0,0},{0,0,0,0}};
  const int arow = bm + wid * 16 + lc;
  const ushort* aptr = A + (size_t)arow * K + quad * 8;

  for (int k0 = 0; k0 < K; k0 += 32){
    short8 bv = *(const short8*)(B + (size_t)(k0 + sk) * N + bn + (scg << 3));
    #pragma unroll
    for (int i = 0; i < 8; ++i){
      int c = (scg << 3) + i;
      int p = c * 40 + (((sk >> 3) ^ (scg & 3)) << 3) + (sk & 7);
      Blds[p] = (ushort)bv[i];
    }
    __syncthreads();
    short8 av = *(const short8*)(aptr + k0);
    #pragma unroll
    for (int nt = 0; nt < 4; ++nt){
      int c2 = (nt << 4) + lc;
      int p  = c2 * 40 + ((quad ^ ((c2 >> 3) & 3)) << 3);
      short8 bfrag = *(const short8*)(Blds + p);
      acc[nt] = MFMA16(av, bfrag, acc[nt]);
    }
    __syncthreads();
  }
  #pragma unroll
  for (int nt = 0; nt < 4; ++nt){
    #pragma unroll
    for (int i = 0; i < 4; ++i){
      int m = bm + wid * 16 + quad * 4 + i;
      int n = bn + (nt << 4) + lc;
      float v = acc[nt][i] + bias[n];
      if (F32OUT) ((float*)Cv)[(size_t)m * N + n] = v;
      else        ((ushort*)Cv)[(size_t)m * N + n] = f2bf(v);
    }
  }
}

// ---------------------------------------------------------------------------
// Fused 3-layer pipelined GRU recurrence, DE-LOCKSTEPPED. 96 WGs x 384 thr.
// r5 + change: roles 1/2 load avx+avm (+ role2 scalars) in ONE batched asm
// block -> 1 L3 round-trip per step instead of 2 (+6 possible scalar RTs).
// ---------------------------------------------------------------------------
#define NWG 96
#define RD 8
#define FSTEPS 1032

__global__ __launch_bounds__(384, 1) void rec3_k(
    const ushort* __restrict__ xw0,   // [32*1024,1536] bf16, row = b*1024+t
    const ushort* __restrict__ R0b,   // [512,1536]
    const ushort* __restrict__ Ksb,   // [512,1536]
    const ushort* __restrict__ Rsb,   // [512,1536]
    const float*  __restrict__ b0v,   // [2,1536]
    const float*  __restrict__ bsv,   // [2,1536]
    const float*  __restrict__ h00,
    const float*  __restrict__ h01,
    const float*  __restrict__ h02,
    const float*  __restrict__ av,    // [3]
    ushort* __restrict__ comb,        // [32*1024,512] bf16
    ushort* __restrict__ rings,
    int* __restrict__ flags)          // [3][FSTEPS][32]
{
  __shared__ float m_lds[3][32][17];
  __shared__ float x_lds[3][32][17];
  __shared__ float bias_l[96];                       // [0:48) b_rec, [48:96) b_in(bs)
  __shared__ __align__(16) ushort ks_lds[3 * 16 * 64 * 8];  // 48 KB

  const int tid  = threadIdx.x;
  const int wid  = tid >> 6;
  const int lane = tid & 63;
  const int quad = lane >> 4;
  const int lc   = lane & 15;
  const int bid  = blockIdx.x;
  const int role = bid >> 5;
  const int g    = bid & 31;
  const int ug0  = g << 4;
  const int gate = wid % 3, mtile = wid / 3;
  const int col0 = (gate << 9) + ug0;

  // ring layout (ushort units): h[3] 131072 each; out0 131072; pred0 131072;
  // xw1 [8][32][512][4] = 524288
  ushort* h_ring    = rings + role * 131072;
  ushort* out0ring  = rings + 393216;
  ushort* pred0ring = rings + 524288;
  ushort* xw1ring   = rings + 655360;

  // ---- recurrent-weight fragments in VGPRs ----
  const ushort* Rw = (role == 0) ? R0b : Rsb;
  short8 bfragR[16];
  #pragma unroll
  for (int f = 0; f < 16; ++f){
    short8 v;
    #pragma unroll
    for (int j = 0; j < 8; ++j)
      v[j] = (short)Rw[(size_t)(f * 32 + quad * 8 + j) * 1536 + col0 + lc];
    bfragR[f] = v;
  }
  // ---- Ks slice into LDS (roles 1,2), one wave per gate ----
  if (role > 0 && mtile == 0){
    #pragma unroll
    for (int f = 0; f < 16; ++f){
      short8 v;
      #pragma unroll
      for (int j = 0; j < 8; ++j)
        v[j] = (short)Ksb[(size_t)(f * 32 + quad * 8 + j) * 1536 + col0 + lc];
      *(short8*)(ks_lds + (((gate << 4) + f) << 9) + (lane << 3)) = v;
    }
  }
  const float* brec = ((role == 0) ? b0v : bsv) + 1536;
  if (tid < 48) bias_l[tid] = brec[(tid >> 4) * 512 + ug0 + (tid & 15)];
  if (tid >= 48 && tid < 96) bias_l[tid] = bsv[((tid - 48) >> 4) * 512 + ug0 + ((tid - 48) & 15)];
  const float a0 = av[0], a1 = av[1], a2 = av[2];
  const float* hinit = (role == 0) ? h00 : (role == 1) ? h01 : h02;

  const int  b0i  = tid >> 4;
  const int  u0   = tid & 15;
  const int  b1i  = (tid + 384) >> 4;
  const bool has1 = (tid < 128);
  const int  uu   = ug0 + u0;
  float hp0 = hinit[uu];
  float hp1 = hp0;

  // ---- role0 xw prefetch for t=0 ----
  ushort xz0 = 0, xr0 = 0, xh0 = 0, xz1 = 0, xr1 = 0, xh1 = 0;
  if (role == 0){
    size_t r0_ = ((size_t)b0i * 1024) * 1536 + uu;
    xz0 = xw0[r0_]; xr0 = xw0[r0_ + 512]; xh0 = xw0[r0_ + 1024];
    if (has1){
      size_t r1_ = ((size_t)b1i * 1024) * 1536 + uu;
      xz1 = xw0[r1_]; xr1 = xw0[r1_ + 512]; xh1 = xw0[r1_ + 1024];
    }
  }
  __syncthreads();

  long budget = 40000000L;  // spin safety valve: degrade, don't hang
  for (int t = 0; t < 1024; ++t){
    const int s     = t + role;
    const int slot  = t & (RD - 1);
    const int pslot = (t - 1) & (RD - 1);

    // role0: prefetch next xw (independent of flags)
    ushort nz0 = 0, nr0 = 0, nh0 = 0, nz1 = 0, nr1 = 0, nh1 = 0;
    if (role == 0 && t < 1023){
      size_t r0_ = ((size_t)b0i * 1024 + t + 1) * 1536 + uu;
      nz0 = xw0[r0_]; nr0 = xw0[r0_ + 512]; nh0 = xw0[r0_ + 1024];
      if (has1){
        size_t r1_ = ((size_t)b1i * 1024 + t + 1) * 1536 + uu;
        nz1 = xw0[r1_]; nr1 = xw0[r1_ + 512]; nh1 = xw0[r1_ + 1024];
      }
    }

    // ---- de-lockstepped wait (unchanged from proven kernel) ----
    {
      const bool needO = (t > 0);                       // own h ring
      const bool needP = (role >= 1);                   // prev-role stream
      const bool needF = (role <= 1) && (s >= RD);      // ring back-pressure
      if ((needO || needP || needF) && wid == 0){
        const int  l    = lane & 31;
        const int* fo   = flags + (role * FSTEPS + (s - 1)) * 32 + l;
        const int* fp   = flags + ((role - 1) * FSTEPS + (s - 1)) * 32 + l;
        const int* ff   = flags + (2 * FSTEPS + (s - 6)) * 32 + l;
        while (budget > 0){
          bool ok = true;
          if (needO) ok &= (__hip_atomic_load(fo, __ATOMIC_RELAXED, __HIP_MEMORY_SCOPE_AGENT) != 0);
          if (needP) ok &= (__hip_atomic_load(fp, __ATOMIC_RELAXED, __HIP_MEMORY_SCOPE_AGENT) != 0);
          if (needF) ok &= (__hip_atomic_load(ff, __ATOMIC_RELAXED, __HIP_MEMORY_SCOPE_AGENT) != 0);
          if (__ballot(ok) == ~0ull) break;
          --budget;
        }
      }
      __syncthreads();
    }

    // ---- A-frags (+ role2 scalars), ONE batched round-trip; then MFMA ----
    float o_s0 = 0, p_s0 = 0, x1z0 = 0, x1r0 = 0, x1h0 = 0;
    float o_s1 = 0, p_s1 = 0, x1z1 = 0, x1r1 = 0, x1h1 = 0;
    {
      short8 avm[16];
      short8 avx[16];
      const ushort* hr  = h_ring + pslot * 16384 + (mtile * 16 + lc) * 512 + quad * 8;
      const ushort* xr_ = ((role == 1) ? out0ring : pred0ring)
                        + slot * 16384 + (mtile * 16 + lc) * 512 + quad * 8;

      if (t == 0){
        #pragma unroll
        for (int f = 0; f < 16; ++f){
          short8 v;
          #pragma unroll
          for (int j = 0; j < 8; ++j)
            v[j] = (short)f2bf(hinit[f * 32 + quad * 8 + j]);
          avm[f] = v;
        }
        if (role >= 1) ld_frag16(xr_, avx);
        if (role == 2){   // one-time scalar path (proven atomics)
          int rb0 = slot * 16384 + b0i * 512 + uu;
          o_s0 = ld_ring_bf(out0ring, rb0);
          p_s0 = ld_ring_bf(pred0ring, rb0);
          ull xwp = __hip_atomic_load((const ull*)(xw1ring + (size_t)((slot * 32 + b0i) * 512 + uu) * 4),
                                      __ATOMIC_RELAXED, __HIP_MEMORY_SCOPE_AGENT);
          x1z0 = bf2f((ushort)(xwp & 0xffffu));
          x1r0 = bf2f((ushort)((xwp >> 16) & 0xffffu));
          x1h0 = bf2f((ushort)((xwp >> 32) & 0xffffu));
          if (has1){
            int rb1 = slot * 16384 + b1i * 512 + uu;
            o_s1 = ld_ring_bf(out0ring, rb1);
            p_s1 = ld_ring_bf(pred0ring, rb1);
            ull xwq = __hip_atomic_load((const ull*)(xw1ring + (size_t)((slot * 32 + b1i) * 512 + uu) * 4),
                                        __ATOMIC_RELAXED, __HIP_MEMORY_SCOPE_AGENT);
            x1z1 = bf2f((ushort)(xwq & 0xffffu));
            x1r1 = bf2f((ushort)((xwq >> 16) & 0xffffu));
            x1h1 = bf2f((ushort)((xwq >> 32) & 0xffffu));
          }
        }
      } else if (role == 0){
        ld_frag16(hr, avm);
      } else if (role == 1){
        ld_frag32(xr_, hr, avx, avm);
      } else {
        int rb0 = slot * 16384 + b0i * 512 + uu;
        int rb1 = slot * 16384 + b1i * 512 + uu;
        const ushort* q0 = out0ring  + (rb0 & ~1);
        const ushort* q1 = pred0ring + (rb0 & ~1);
        const ushort* q2 = xw1ring + (size_t)((slot * 32 + b0i) * 512 + uu) * 4;
        const ushort* q3 = has1 ? (out0ring  + (rb1 & ~1)) : q0;
        const ushort* q4 = has1 ? (pred0ring + (rb1 & ~1)) : q1;
        const ushort* q5 = has1 ? (xw1ring + (size_t)((slot * 32 + b1i) * 512 + uu) * 4) : q2;
        unsigned int w0, w1, w3, w4; ull w2, w5;
        ld_frag32s(xr_, hr, q0, q1, q2, q3, q4, q5,
                   avx, avm, &w0, &w1, &w2, &w3, &w4, &w5);
        int hi = uu & 1;
        o_s0 = bf2f(hi ? (ushort)(w0 >> 16) : (ushort)(w0 & 0xffffu));
        p_s0 = bf2f(hi ? (ushort)(w1 >> 16) : (ushort)(w1 & 0xffffu));
        x1z0 = bf2f((ushort)(w2 & 0xffffu));
        x1r0 = bf2f((ushort)((w2 >> 16) & 0xffffu));
        x1h0 = bf2f((ushort)((w2 >> 32) & 0xffffu));
        if (has1){
          o_s1 = bf2f(hi ? (ushort)(w3 >> 16) : (ushort)(w3 & 0xffffu));
          p_s1 = bf2f(hi ? (ushort)(w4 >> 16) : (ushort)(w4 & 0xffffu));
          x1z1 = bf2f((ushort)(w5 & 0xffffu));
          x1r1 = bf2f((ushort)((w5 >> 16) & 0xffffu));
          x1h1 = bf2f((ushort)((w5 >> 32) & 0xffffu));
        }
      }

      f32x4 am0 = {0,0,0,0}, am1 = {0,0,0,0};
      if (role == 0){
        #pragma unroll
        for (int f = 0; f < 16; ++f){
          if (f & 1) am1 = MFMA16(avm[f], bfragR[f], am1);
          else       am0 = MFMA16(avm[f], bfragR[f], am0);
        }
        f32x4 am = am0 + am1;
        #pragma unroll
        for (int i = 0; i < 4; ++i)
          m_lds[gate][(mtile << 4) + (quad << 2) + i][lc] = am[i];
      } else {
        f32x4 ax0 = {0,0,0,0}, ax1 = {0,0,0,0};
        #pragma unroll
        for (int f = 0; f < 16; ++f){
          short8 bx = *(const short8*)(ks_lds + (((gate << 4) + f) << 9) + (lane << 3));
          if (f & 1){ am1 = MFMA16(avm[f], bfragR[f], am1); ax1 = MFMA16(avx[f], bx, ax1); }
          else      { am0 = MFMA16(avm[f], bfragR[f], am0); ax0 = MFMA16(avx[f], bx, ax0); }
        }
        f32x4 am = am0 + am1, ax = ax0 + ax1;
        #pragma unroll
        for (int i = 0; i < 4; ++i){
          m_lds[gate][(mtile << 4) + (quad << 2) + i][lc] = am[i];
          x_lds[gate][(mtile << 4) + (quad << 2) + i][lc] = ax[i];
        }
      }
    }
    __syncthreads();

    // ---- gate math; ring stores only (publish-early) ----
    ushort cb0 = 0, cb1 = 0;
    {
      int b = b0i;
      float mz = m_lds[0][b][u0] + bias_l[u0];
      float mr = m_lds[1][b][u0] + bias_l[16 + u0];
      float mh = m_lds[2][b][u0] + bias_l[32 + u0];
      float xz, xr, xh;
      if (role == 0){ xz = bf2f(xz0); xr = bf2f(xr0); xh = bf2f(xh0); }
      else if (role == 1){
        xz = x_lds[0][b][u0] + bias_l[48 + u0];
        xr = x_lds[1][b][u0] + bias_l[64 + u0];
        xh = x_lds[2][b][u0] + bias_l[80 + u0];
      } else {
        xz = x1z0 + a0 * x_lds[0][b][u0] + bias_l[48 + u0];
        xr = x1r0 + a0 * x_lds[1][b][u0] + bias_l[64 + u0];
        xh = x1h0 + a0 * x_lds[2][b][u0] + bias_l[80 + u0];
      }
      float z  = 1.f / (1.f + __expf(-(xz + mz)));
      float r  = 1.f / (1.f + __expf(-(xr + mr)));
      float axv = xh + r * mh;
      float hh = 1.f - 2.f / (1.f + __expf(2.f * axv));
      float hn = z * hp0 + (1.f - z) * hh;
      float hcv = hn + 0.1f * (hp0 - hn);
      hp0 = hcv;
      int rb = slot * 16384 + b * 512 + uu;
      st_hc2(h_ring + rb, f2bf(hcv));
      if (role == 0) st_hc2(out0ring + rb, f2bf(hn));
      else if (role == 1){
        st_hc2(pred0ring + rb, f2bf(hn));
        ull pv = (ull)f2bf(x_lds[0][b][u0])
               | ((ull)f2bf(x_lds[1][b][u0]) << 16)
               | ((ull)f2bf(x_lds[2][b][u0]) << 32);
        st_hc8(xw1ring + (size_t)((slot * 32 + b) * 512 + uu) * 4, pv);
      } else {
        cb0 = f2bf(o_s0 + a1 * p_s0 + a2 * hn);
      }
    }
    if (has1){
      int b = b1i;
      float mz = m_lds[0][b][u0] + bias_l[u0];
      float mr = m_lds[1][b][u0] + bias_l[16 + u0];
      float mh = m_lds[2][b][u0] + bias_l[32 + u0];
      float xz, xr, xh;
      if (role == 0){ xz = bf2f(xz1); xr = bf2f(xr1); xh = bf2f(xh1); }
      else if (role == 1){
        xz = x_lds[0][b][u0] + bias_l[48 + u0];
        xr = x_lds[1][b][u0] + bias_l[64 + u0];
        xh = x_lds[2][b][u0] + bias_l[80 + u0];
      } else {
        xz = x1z1 + a0 * x_lds[0][b][u0] + bias_l[48 + u0];
        xr = x1r1 + a0 * x_lds[1][b][u0] + bias_l[64 + u0];
        xh = x1h1 + a0 * x_lds[2][b][u0] + bias_l[80 + u0];
      }
      float z  = 1.f / (1.f + __expf(-(xz + mz)));
      float r  = 1.f / (1.f + __expf(-(xr + mr)));
      float axv = xh + r * mh;
      float hh = 1.f - 2.f / (1.f + __expf(2.f * axv));
      float hn = z * hp1 + (1.f - z) * hh;
      float hcv = hn + 0.1f * (hp1 - hn);
      hp1 = hcv;
      int rb = slot * 16384 + b * 512 + uu;
      st_hc2(h_ring + rb, f2bf(hcv));
      if (role == 0) st_hc2(out0ring + rb, f2bf(hn));
      else if (role == 1){
        st_hc2(pred0ring + rb, f2bf(hn));
        ull pv = (ull)f2bf(x_lds[0][b][u0])
               | ((ull)f2bf(x_lds[1][b][u0]) << 16)
               | ((ull)f2bf(x_lds[2][b][u0]) << 32);
        st_hc8(xw1ring + (size_t)((slot * 32 + b) * 512 + uu) * 4, pv);
      } else {
        cb1 = f2bf(o_s1 + a1 * p_s1 + a2 * hn);
      }
    }
    asm volatile("s_waitcnt vmcnt(0)" ::: "memory");  // ring stores at coherence pt
    __syncthreads();
    if (tid == 0)
      __hip_atomic_store(flags + (role * FSTEPS + s) * 32 + g, 1,
                         __ATOMIC_RELAXED, __HIP_MEMORY_SCOPE_AGENT);
    // role2 HBM output AFTER publish: off the critical path
    if (role == 2){
      comb[((size_t)b0i * 1024 + t) * 512 + uu] = cb0;
      if (has1) comb[((size_t)b1i * 1024 + t) * 512 + uu] = cb1;
    }

    if (role == 0){
      xz0 = nz0; xr0 = nr0; xh0 = nh0;
      xz1 = nz1; xr1 = nr1; xh1 = nh1;
    }
  }
}

// ---------------------------------------------------------------------------
extern "C" void kernel_launch(void* const* d_in, const int* in_sizes, int n_in,
                              void* d_out, int out_size, void* d_ws, size_t ws_size,
                              hipStream_t stream)
{
  const float* x   = (const float*)d_in[0];
  const float* k0  = (const float*)d_in[1];
  const float* r0  = (const float*)d_in[2];
  const float* b0  = (const float*)d_in[3];
  const float* ks  = (const float*)d_in[4];
  const float* rs  = (const float*)d_in[5];
  const float* bs  = (const float*)d_in[6];
  const float* h00 = (const float*)d_in[7];
  const float* h01 = (const float*)d_in[8];
  const float* h02 = (const float*)d_in[9];
  const float* a   = (const float*)d_in[10];
  const float* wd  = (const float*)d_in[11];
  const float* bd  = (const float*)d_in[12];
  float* outp = (float*)d_out;

  // ws layout (bytes), ~142.8 MB total:
  //   [0,        100663296)  XW0   [32768,1536] bf16
  //   [100663296,134217728)  comb  [32768,512] bf16 (first 16.8MB aliases x_bf)
  //   [134217728,136577024)  rings (2.25 MB)
  //   [136577024,136973312)  flags [3][1032][32] int
  //   [136973312,...]        bf16 weights k0b,r0b,ksb,rsb,wdb
  char* ws = (char*)d_ws;
  ushort* XW    = (ushort*)(ws);
  ushort* combp = (ushort*)(ws + 100663296u);
  ushort* xbf   = combp;                      // alias: dead before rec3_k runs
  ushort* rings = (ushort*)(ws + 134217728u);
  int*    flags = (int*)   (ws + 136577024u);
  ushort* k0b   = (ushort*)(ws + 136973312u);
  ushort* r0b   = (ushort*)(ws + 137759744u);
  ushort* ksb   = (ushort*)(ws + 139332608u);
  ushort* rsb   = (ushort*)(ws + 140905472u);
  ushort* wdb   = (ushort*)(ws + 142478336u);

  hipMemsetAsync(flags, 0, 3 * FSTEPS * 32 * sizeof(int), stream);

  dim3 blk(256);
  cvt_k<<<dim3(8192), blk, 0, stream>>>(x,  xbf, 8388608);
  cvt_k<<<dim3(384),  blk, 0, stream>>>(k0, k0b, 393216);
  cvt_k<<<dim3(768),  blk, 0, stream>>>(r0, r0b, 786432);
  cvt_k<<<dim3(768),  blk, 0, stream>>>(ks, ksb, 786432);
  cvt_k<<<dim3(768),  blk, 0, stream>>>(rs, rsb, 786432);
  cvt_k<<<dim3(128),  blk, 0, stream>>>(wd, wdb, 131072);

  // Layer-0 input projection (bulk GEMM)
  gemm_bias_k<0><<<dim3(512 * 24), blk, 0, stream>>>(xbf, k0b, b0, XW, 32768, 1536, 256);
  // Fused pipelined 3-layer recurrence (de-lockstepped, single-RT ring loads)
  rec3_k<<<dim3(NWG), dim3(384), 0, stream>>>(XW, r0b, ksb, rsb, b0, bs,
                                              h00, h01, h02, a, combp, rings, flags);
  // Final projection: comb @ wd + bd -> fp32 d_out
  gemm_bias_k<1><<<dim3(512 * 4), blk, 0, stream>>>(combp, wdb, bd, outp, 32768, 256, 512);
}

// Round 7
// 10476.302 us; speedup vs baseline: 1.2106x; 1.2106x over previous
//
#include <hip/hip_runtime.h>

typedef __attribute__((ext_vector_type(8))) short short8;
typedef __attribute__((ext_vector_type(4))) float f32x4;
typedef __attribute__((ext_vector_type(4))) unsigned short u16x4;
typedef unsigned short ushort;
typedef unsigned long long ull;

#define MFMA16(a,b,c) __builtin_amdgcn_mfma_f32_16x16x32_bf16((a),(b),(c),0,0,0)

static __device__ __forceinline__ float bf2f(ushort u){
  union { unsigned int i; float f; } z; z.i = ((unsigned int)u) << 16; return z.f;
}
static __device__ __forceinline__ ushort f2bf(float f){
  union { float f; unsigned int i; } z; z.f = f;
  unsigned int x = z.i;
  unsigned int r = (x + 0x7fffu + ((x >> 16) & 1u)) >> 16;   // RNE
  return (ushort)r;
}

// single bf16 from ring via aligned u32 agent atomic (proven)
static __device__ __forceinline__ float ld_ring_bf(const ushort* base, int idx){
  const unsigned int* p = (const unsigned int*)(base + (idx & ~1));
  unsigned int w = __hip_atomic_load(p, __ATOMIC_RELAXED, __HIP_MEMORY_SCOPE_AGENT);
  return bf2f((idx & 1) ? (ushort)(w >> 16) : (ushort)(w & 0xffffu));
}
// 2B / 8B write-through stores to coherence point (proven)
static __device__ __forceinline__ void st_hc2(ushort* p, ushort v){
  unsigned int vv = v;
  asm volatile("global_store_short %0, %1, off sc0 sc1" :: "v"(p), "v"(vv) : "memory");
}
static __device__ __forceinline__ void st_hc8(ushort* p, ull v){
  asm volatile("global_store_dwordx2 %0, %1, off sc0 sc1" :: "v"(p), "v"(v) : "memory");
}

// ---- batched 16-fragment system-scope load, wait INSIDE the asm (proven r5).
static __device__ __forceinline__ void ld_frag16(const ushort* p, short8* o){
  asm volatile(
    "global_load_dwordx4 %0, %16, off sc0 sc1\n\t"
    "global_load_dwordx4 %1, %16, off offset:64 sc0 sc1\n\t"
    "global_load_dwordx4 %2, %16, off offset:128 sc0 sc1\n\t"
    "global_load_dwordx4 %3, %16, off offset:192 sc0 sc1\n\t"
    "global_load_dwordx4 %4, %16, off offset:256 sc0 sc1\n\t"
    "global_load_dwordx4 %5, %16, off offset:320 sc0 sc1\n\t"
    "global_load_dwordx4 %6, %16, off offset:384 sc0 sc1\n\t"
    "global_load_dwordx4 %7, %16, off offset:448 sc0 sc1\n\t"
    "global_load_dwordx4 %8, %16, off offset:512 sc0 sc1\n\t"
    "global_load_dwordx4 %9, %16, off offset:576 sc0 sc1\n\t"
    "global_load_dwordx4 %10, %16, off offset:640 sc0 sc1\n\t"
    "global_load_dwordx4 %11, %16, off offset:704 sc0 sc1\n\t"
    "global_load_dwordx4 %12, %16, off offset:768 sc0 sc1\n\t"
    "global_load_dwordx4 %13, %16, off offset:832 sc0 sc1\n\t"
    "global_load_dwordx4 %14, %16, off offset:896 sc0 sc1\n\t"
    "global_load_dwordx4 %15, %16, off offset:960 sc0 sc1\n\t"
    "s_waitcnt vmcnt(0)"
    : "=&v"(o[0]), "=&v"(o[1]), "=&v"(o[2]), "=&v"(o[3]),
      "=&v"(o[4]), "=&v"(o[5]), "=&v"(o[6]), "=&v"(o[7]),
      "=&v"(o[8]), "=&v"(o[9]), "=&v"(o[10]), "=&v"(o[11]),
      "=&v"(o[12]), "=&v"(o[13]), "=&v"(o[14]), "=&v"(o[15])
    : "v"(p)
    : "memory");
  __builtin_amdgcn_sched_barrier(0);
}

// ---- dual-base 32-fragment batched load: one in-flight batch, single wait.
static __device__ __forceinline__ void ld_frag32(const ushort* pa, const ushort* pb,
                                                 short8* oa, short8* ob){
  asm volatile(
    "global_load_dwordx4 %0, %32, off sc0 sc1\n\t"
    "global_load_dwordx4 %1, %32, off offset:64 sc0 sc1\n\t"
    "global_load_dwordx4 %2, %32, off offset:128 sc0 sc1\n\t"
    "global_load_dwordx4 %3, %32, off offset:192 sc0 sc1\n\t"
    "global_load_dwordx4 %4, %32, off offset:256 sc0 sc1\n\t"
    "global_load_dwordx4 %5, %32, off offset:320 sc0 sc1\n\t"
    "global_load_dwordx4 %6, %32, off offset:384 sc0 sc1\n\t"
    "global_load_dwordx4 %7, %32, off offset:448 sc0 sc1\n\t"
    "global_load_dwordx4 %8, %32, off offset:512 sc0 sc1\n\t"
    "global_load_dwordx4 %9, %32, off offset:576 sc0 sc1\n\t"
    "global_load_dwordx4 %10, %32, off offset:640 sc0 sc1\n\t"
    "global_load_dwordx4 %11, %32, off offset:704 sc0 sc1\n\t"
    "global_load_dwordx4 %12, %32, off offset:768 sc0 sc1\n\t"
    "global_load_dwordx4 %13, %32, off offset:832 sc0 sc1\n\t"
    "global_load_dwordx4 %14, %32, off offset:896 sc0 sc1\n\t"
    "global_load_dwordx4 %15, %32, off offset:960 sc0 sc1\n\t"
    "global_load_dwordx4 %16, %33, off sc0 sc1\n\t"
    "global_load_dwordx4 %17, %33, off offset:64 sc0 sc1\n\t"
    "global_load_dwordx4 %18, %33, off offset:128 sc0 sc1\n\t"
    "global_load_dwordx4 %19, %33, off offset:192 sc0 sc1\n\t"
    "global_load_dwordx4 %20, %33, off offset:256 sc0 sc1\n\t"
    "global_load_dwordx4 %21, %33, off offset:320 sc0 sc1\n\t"
    "global_load_dwordx4 %22, %33, off offset:384 sc0 sc1\n\t"
    "global_load_dwordx4 %23, %33, off offset:448 sc0 sc1\n\t"
    "global_load_dwordx4 %24, %33, off offset:512 sc0 sc1\n\t"
    "global_load_dwordx4 %25, %33, off offset:576 sc0 sc1\n\t"
    "global_load_dwordx4 %26, %33, off offset:640 sc0 sc1\n\t"
    "global_load_dwordx4 %27, %33, off offset:704 sc0 sc1\n\t"
    "global_load_dwordx4 %28, %33, off offset:768 sc0 sc1\n\t"
    "global_load_dwordx4 %29, %33, off offset:832 sc0 sc1\n\t"
    "global_load_dwordx4 %30, %33, off offset:896 sc0 sc1\n\t"
    "global_load_dwordx4 %31, %33, off offset:960 sc0 sc1\n\t"
    "s_waitcnt vmcnt(0)"
    : "=&v"(oa[0]), "=&v"(oa[1]), "=&v"(oa[2]), "=&v"(oa[3]),
      "=&v"(oa[4]), "=&v"(oa[5]), "=&v"(oa[6]), "=&v"(oa[7]),
      "=&v"(oa[8]), "=&v"(oa[9]), "=&v"(oa[10]), "=&v"(oa[11]),
      "=&v"(oa[12]), "=&v"(oa[13]), "=&v"(oa[14]), "=&v"(oa[15]),
      "=&v"(ob[0]), "=&v"(ob[1]), "=&v"(ob[2]), "=&v"(ob[3]),
      "=&v"(ob[4]), "=&v"(ob[5]), "=&v"(ob[6]), "=&v"(ob[7]),
      "=&v"(ob[8]), "=&v"(ob[9]), "=&v"(ob[10]), "=&v"(ob[11]),
      "=&v"(ob[12]), "=&v"(ob[13]), "=&v"(ob[14]), "=&v"(ob[15])
    : "v"(pa), "v"(pb)
    : "memory");
  __builtin_amdgcn_sched_barrier(0);
}

// ---- role2 variant: 32 fragments + 6 scalar ring words, all in one batch.
static __device__ __forceinline__ void ld_frag32s(
    const ushort* pa, const ushort* pb,
    const ushort* q0, const ushort* q1, const ushort* q2,
    const ushort* q3, const ushort* q4, const ushort* q5,
    short8* oa, short8* ob,
    unsigned int* s0, unsigned int* s1, ull* s2,
    unsigned int* s3, unsigned int* s4, ull* s5)
{
  asm volatile(
    "global_load_dwordx4 %0, %38, off sc0 sc1\n\t"
    "global_load_dwordx4 %1, %38, off offset:64 sc0 sc1\n\t"
    "global_load_dwordx4 %2, %38, off offset:128 sc0 sc1\n\t"
    "global_load_dwordx4 %3, %38, off offset:192 sc0 sc1\n\t"
    "global_load_dwordx4 %4, %38, off offset:256 sc0 sc1\n\t"
    "global_load_dwordx4 %5, %38, off offset:320 sc0 sc1\n\t"
    "global_load_dwordx4 %6, %38, off offset:384 sc0 sc1\n\t"
    "global_load_dwordx4 %7, %38, off offset:448 sc0 sc1\n\t"
    "global_load_dwordx4 %8, %38, off offset:512 sc0 sc1\n\t"
    "global_load_dwordx4 %9, %38, off offset:576 sc0 sc1\n\t"
    "global_load_dwordx4 %10, %38, off offset:640 sc0 sc1\n\t"
    "global_load_dwordx4 %11, %38, off offset:704 sc0 sc1\n\t"
    "global_load_dwordx4 %12, %38, off offset:768 sc0 sc1\n\t"
    "global_load_dwordx4 %13, %38, off offset:832 sc0 sc1\n\t"
    "global_load_dwordx4 %14, %38, off offset:896 sc0 sc1\n\t"
    "global_load_dwordx4 %15, %38, off offset:960 sc0 sc1\n\t"
    "global_load_dwordx4 %16, %39, off sc0 sc1\n\t"
    "global_load_dwordx4 %17, %39, off offset:64 sc0 sc1\n\t"
    "global_load_dwordx4 %18, %39, off offset:128 sc0 sc1\n\t"
    "global_load_dwordx4 %19, %39, off offset:192 sc0 sc1\n\t"
    "global_load_dwordx4 %20, %39, off offset:256 sc0 sc1\n\t"
    "global_load_dwordx4 %21, %39, off offset:320 sc0 sc1\n\t"
    "global_load_dwordx4 %22, %39, off offset:384 sc0 sc1\n\t"
    "global_load_dwordx4 %23, %39, off offset:448 sc0 sc1\n\t"
    "global_load_dwordx4 %24, %39, off offset:512 sc0 sc1\n\t"
    "global_load_dwordx4 %25, %39, off offset:576 sc0 sc1\n\t"
    "global_load_dwordx4 %26, %39, off offset:640 sc0 sc1\n\t"
    "global_load_dwordx4 %27, %39, off offset:704 sc0 sc1\n\t"
    "global_load_dwordx4 %28, %39, off offset:768 sc0 sc1\n\t"
    "global_load_dwordx4 %29, %39, off offset:832 sc0 sc1\n\t"
    "global_load_dwordx4 %30, %39, off offset:896 sc0 sc1\n\t"
    "global_load_dwordx4 %31, %39, off offset:960 sc0 sc1\n\t"
    "global_load_dword %32, %40, off sc0 sc1\n\t"
    "global_load_dword %33, %41, off sc0 sc1\n\t"
    "global_load_dwordx2 %34, %42, off sc0 sc1\n\t"
    "global_load_dword %35, %43, off sc0 sc1\n\t"
    "global_load_dword %36, %44, off sc0 sc1\n\t"
    "global_load_dwordx2 %37, %45, off sc0 sc1\n\t"
    "s_waitcnt vmcnt(0)"
    : "=&v"(oa[0]), "=&v"(oa[1]), "=&v"(oa[2]), "=&v"(oa[3]),
      "=&v"(oa[4]), "=&v"(oa[5]), "=&v"(oa[6]), "=&v"(oa[7]),
      "=&v"(oa[8]), "=&v"(oa[9]), "=&v"(oa[10]), "=&v"(oa[11]),
      "=&v"(oa[12]), "=&v"(oa[13]), "=&v"(oa[14]), "=&v"(oa[15]),
      "=&v"(ob[0]), "=&v"(ob[1]), "=&v"(ob[2]), "=&v"(ob[3]),
      "=&v"(ob[4]), "=&v"(ob[5]), "=&v"(ob[6]), "=&v"(ob[7]),
      "=&v"(ob[8]), "=&v"(ob[9]), "=&v"(ob[10]), "=&v"(ob[11]),
      "=&v"(ob[12]), "=&v"(ob[13]), "=&v"(ob[14]), "=&v"(ob[15]),
      "=&v"(*s0), "=&v"(*s1), "=&v"(*s2), "=&v"(*s3), "=&v"(*s4), "=&v"(*s5)
    : "v"(pa), "v"(pb), "v"(q0), "v"(q1), "v"(q2), "v"(q3), "v"(q4), "v"(q5)
    : "memory");
  __builtin_amdgcn_sched_barrier(0);
}

// ---------------------------------------------------------------------------
// fp32 -> bf16 convert, 4 elems/thread
// ---------------------------------------------------------------------------
__global__ __launch_bounds__(256) void cvt_k(
    const float* __restrict__ in, ushort* __restrict__ out, int n)
{
  int i = (blockIdx.x * 256 + threadIdx.x) * 4;
  if (i < n){
    float4 v = *(const float4*)(in + i);
    u16x4 o = { f2bf(v.x), f2bf(v.y), f2bf(v.z), f2bf(v.w) };
    *(u16x4*)(out + i) = o;
  }
}

// ---------------------------------------------------------------------------
// GEMM: C[M,N] = A[M,K](bf16) @ B[K,N](bf16) + bias[N](fp32).
// ---------------------------------------------------------------------------
template<int F32OUT>
__global__ __launch_bounds__(256) void gemm_bias_k(
    const ushort* __restrict__ A,
    const ushort* __restrict__ B,
    const float*  __restrict__ bias,
    void* __restrict__ Cv,
    int M, int N, int K)
{
  __shared__ __align__(16) ushort Blds[64 * 40];
  const int tid  = threadIdx.x;
  const int wid  = tid >> 6;
  const int lane = tid & 63;
  const int quad = lane >> 4;
  const int lc   = lane & 15;
  const int nb   = N >> 6;
  const int bn   = (blockIdx.x % nb) << 6;
  const int bm   = (blockIdx.x / nb) << 6;

  const int sk  = tid >> 3;
  const int scg = tid & 7;

  f32x4 acc[4] = {{0,0,0,0},{0,0,0,0},{0,0,0,0},{0,0,0,0}};
  const int arow = bm + wid * 16 + lc;
  const ushort* aptr = A + (size_t)arow * K + quad * 8;

  for (int k0 = 0; k0 < K; k0 += 32){
    short8 bv = *(const short8*)(B + (size_t)(k0 + sk) * N + bn + (scg << 3));
    #pragma unroll
    for (int i = 0; i < 8; ++i){
      int c = (scg << 3) + i;
      int p = c * 40 + (((sk >> 3) ^ (scg & 3)) << 3) + (sk & 7);
      Blds[p] = (ushort)bv[i];
    }
    __syncthreads();
    short8 av = *(const short8*)(aptr + k0);
    #pragma unroll
    for (int nt = 0; nt < 4; ++nt){
      int c2 = (nt << 4) + lc;
      int p  = c2 * 40 + ((quad ^ ((c2 >> 3) & 3)) << 3);
      short8 bfrag = *(const short8*)(Blds + p);
      acc[nt] = MFMA16(av, bfrag, acc[nt]);
    }
    __syncthreads();
  }
  #pragma unroll
  for (int nt = 0; nt < 4; ++nt){
    #pragma unroll
    for (int i = 0; i < 4; ++i){
      int m = bm + wid * 16 + quad * 4 + i;
      int n = bn + (nt << 4) + lc;
      float v = acc[nt][i] + bias[n];
      if (F32OUT) ((float*)Cv)[(size_t)m * N + n] = v;
      else        ((ushort*)Cv)[(size_t)m * N + n] = f2bf(v);
    }
  }
}

// ---------------------------------------------------------------------------
// Fused 3-layer pipelined GRU recurrence, DE-LOCKSTEPPED. 96 WGs x 384 thr.
// r5 protocol. Roles 1/2: Rs weights in LDS (frees 64 VGPRs) so the merged
// single-RT 32-fragment load fits WITHOUT spilling (r6's failure mode).
// Role 0: unchanged r5 path (bfragR in VGPRs, 16-frag load).
// ---------------------------------------------------------------------------
#define NWG 96
#define RD 8
#define FSTEPS 1032

__global__ __launch_bounds__(384, 1) void rec3_k(
    const ushort* __restrict__ xw0,   // [32*1024,1536] bf16, row = b*1024+t
    const ushort* __restrict__ R0b,   // [512,1536]
    const ushort* __restrict__ Ksb,   // [512,1536]
    const ushort* __restrict__ Rsb,   // [512,1536]
    const float*  __restrict__ b0v,   // [2,1536]
    const float*  __restrict__ bsv,   // [2,1536]
    const float*  __restrict__ h00,
    const float*  __restrict__ h01,
    const float*  __restrict__ h02,
    const float*  __restrict__ av,    // [3]
    ushort* __restrict__ comb,        // [32*1024,512] bf16
    ushort* __restrict__ rings,
    int* __restrict__ flags)          // [3][FSTEPS][32]
{
  __shared__ float m_lds[3][32][17];
  __shared__ float x_lds[3][32][17];
  __shared__ float bias_l[96];                       // [0:48) b_rec, [48:96) b_in(bs)
  __shared__ __align__(16) ushort ks_lds[3 * 16 * 64 * 8];  // 48 KB
  __shared__ __align__(16) ushort rs_lds[3 * 16 * 64 * 8];  // 48 KB (roles 1/2)

  const int tid  = threadIdx.x;
  const int wid  = tid >> 6;
  const int lane = tid & 63;
  const int quad = lane >> 4;
  const int lc   = lane & 15;
  const int bid  = blockIdx.x;
  const int role = bid >> 5;
  const int g    = bid & 31;
  const int ug0  = g << 4;
  const int gate = wid % 3, mtile = wid / 3;
  const int col0 = (gate << 9) + ug0;

  // ring layout (ushort units): h[3] 131072 each; out0 131072; pred0 131072;
  // xw1 [8][32][512][4] = 524288
  ushort* h_ring    = rings + role * 131072;
  ushort* out0ring  = rings + 393216;
  ushort* pred0ring = rings + 524288;
  ushort* xw1ring   = rings + 655360;

  // ---- role 0 ONLY: R0 fragments in VGPRs (liveness confined to role0 path)
  short8 bfragR[16];
  if (role == 0){
    #pragma unroll
    for (int f = 0; f < 16; ++f){
      short8 v;
      #pragma unroll
      for (int j = 0; j < 8; ++j)
        v[j] = (short)R0b[(size_t)(f * 32 + quad * 8 + j) * 1536 + col0 + lc];
      bfragR[f] = v;
    }
  }
  // ---- roles 1/2: Ks (mtile0 waves) and Rs (mtile1 waves) into LDS ----
  if (role > 0){
    if (mtile == 0){
      #pragma unroll
      for (int f = 0; f < 16; ++f){
        short8 v;
        #pragma unroll
        for (int j = 0; j < 8; ++j)
          v[j] = (short)Ksb[(size_t)(f * 32 + quad * 8 + j) * 1536 + col0 + lc];
        *(short8*)(ks_lds + (((gate << 4) + f) << 9) + (lane << 3)) = v;
      }
    } else {
      #pragma unroll
      for (int f = 0; f < 16; ++f){
        short8 v;
        #pragma unroll
        for (int j = 0; j < 8; ++j)
          v[j] = (short)Rsb[(size_t)(f * 32 + quad * 8 + j) * 1536 + col0 + lc];
        *(short8*)(rs_lds + (((gate << 4) + f) << 9) + (lane << 3)) = v;
      }
    }
  }
  const float* brec = ((role == 0) ? b0v : bsv) + 1536;
  if (tid < 48) bias_l[tid] = brec[(tid >> 4) * 512 + ug0 + (tid & 15)];
  if (tid >= 48 && tid < 96) bias_l[tid] = bsv[((tid - 48) >> 4) * 512 + ug0 + ((tid - 48) & 15)];
  const float a0 = av[0], a1 = av[1], a2 = av[2];
  const float* hinit = (role == 0) ? h00 : (role == 1) ? h01 : h02;

  const int  b0i  = tid >> 4;
  const int  u0   = tid & 15;
  const int  b1i  = (tid + 384) >> 4;
  const bool has1 = (tid < 128);
  const int  uu   = ug0 + u0;
  float hp0 = hinit[uu];
  float hp1 = hp0;

  // ---- role0 xw prefetch for t=0 ----
  ushort xz0 = 0, xr0 = 0, xh0 = 0, xz1 = 0, xr1 = 0, xh1 = 0;
  if (role == 0){
    size_t r0_ = ((size_t)b0i * 1024) * 1536 + uu;
    xz0 = xw0[r0_]; xr0 = xw0[r0_ + 512]; xh0 = xw0[r0_ + 1024];
    if (has1){
      size_t r1_ = ((size_t)b1i * 1024) * 1536 + uu;
      xz1 = xw0[r1_]; xr1 = xw0[r1_ + 512]; xh1 = xw0[r1_ + 1024];
    }
  }
  __syncthreads();

  long budget = 40000000L;  // spin safety valve: degrade, don't hang
  for (int t = 0; t < 1024; ++t){
    const int s     = t + role;
    const int slot  = t & (RD - 1);
    const int pslot = (t - 1) & (RD - 1);

    // role0: prefetch next xw (independent of flags)
    ushort nz0 = 0, nr0 = 0, nh0 = 0, nz1 = 0, nr1 = 0, nh1 = 0;
    if (role == 0 && t < 1023){
      size_t r0_ = ((size_t)b0i * 1024 + t + 1) * 1536 + uu;
      nz0 = xw0[r0_]; nr0 = xw0[r0_ + 512]; nh0 = xw0[r0_ + 1024];
      if (has1){
        size_t r1_ = ((size_t)b1i * 1024 + t + 1) * 1536 + uu;
        nz1 = xw0[r1_]; nr1 = xw0[r1_ + 512]; nh1 = xw0[r1_ + 1024];
      }
    }

    // ---- de-lockstepped wait (unchanged from proven kernel) ----
    {
      const bool needO = (t > 0);                       // own h ring
      const bool needP = (role >= 1);                   // prev-role stream
      const bool needF = (role <= 1) && (s >= RD);      // ring back-pressure
      if ((needO || needP || needF) && wid == 0){
        const int  l    = lane & 31;
        const int* fo   = flags + (role * FSTEPS + (s - 1)) * 32 + l;
        const int* fp   = flags + ((role - 1) * FSTEPS + (s - 1)) * 32 + l;
        const int* ff   = flags + (2 * FSTEPS + (s - 6)) * 32 + l;
        while (budget > 0){
          bool ok = true;
          if (needO) ok &= (__hip_atomic_load(fo, __ATOMIC_RELAXED, __HIP_MEMORY_SCOPE_AGENT) != 0);
          if (needP) ok &= (__hip_atomic_load(fp, __ATOMIC_RELAXED, __HIP_MEMORY_SCOPE_AGENT) != 0);
          if (needF) ok &= (__hip_atomic_load(ff, __ATOMIC_RELAXED, __HIP_MEMORY_SCOPE_AGENT) != 0);
          if (__ballot(ok) == ~0ull) break;
          --budget;
        }
      }
      __syncthreads();
    }

    // ---- A-frags (+ role2 scalars), ONE batched round-trip; then MFMA ----
    float o_s0 = 0, p_s0 = 0, x1z0 = 0, x1r0 = 0, x1h0 = 0;
    float o_s1 = 0, p_s1 = 0, x1z1 = 0, x1r1 = 0, x1h1 = 0;
    {
      short8 avm[16];
      short8 avx[16];
      const ushort* hr  = h_ring + pslot * 16384 + (mtile * 16 + lc) * 512 + quad * 8;
      const ushort* xr_ = ((role == 1) ? out0ring : pred0ring)
                        + slot * 16384 + (mtile * 16 + lc) * 512 + quad * 8;

      if (t == 0){
        #pragma unroll
        for (int f = 0; f < 16; ++f){
          short8 v;
          #pragma unroll
          for (int j = 0; j < 8; ++j)
            v[j] = (short)f2bf(hinit[f * 32 + quad * 8 + j]);
          avm[f] = v;
        }
        if (role >= 1) ld_frag16(xr_, avx);
        if (role == 2){   // one-time scalar path (proven atomics)
          int rb0 = slot * 16384 + b0i * 512 + uu;
          o_s0 = ld_ring_bf(out0ring, rb0);
          p_s0 = ld_ring_bf(pred0ring, rb0);
          ull xwp = __hip_atomic_load((const ull*)(xw1ring + (size_t)((slot * 32 + b0i) * 512 + uu) * 4),
                                      __ATOMIC_RELAXED, __HIP_MEMORY_SCOPE_AGENT);
          x1z0 = bf2f((ushort)(xwp & 0xffffu));
          x1r0 = bf2f((ushort)((xwp >> 16) & 0xffffu));
          x1h0 = bf2f((ushort)((xwp >> 32) & 0xffffu));
          if (has1){
            int rb1 = slot * 16384 + b1i * 512 + uu;
            o_s1 = ld_ring_bf(out0ring, rb1);
            p_s1 = ld_ring_bf(pred0ring, rb1);
            ull xwq = __hip_atomic_load((const ull*)(xw1ring + (size_t)((slot * 32 + b1i) * 512 + uu) * 4),
                                        __ATOMIC_RELAXED, __HIP_MEMORY_SCOPE_AGENT);
            x1z1 = bf2f((ushort)(xwq & 0xffffu));
            x1r1 = bf2f((ushort)((xwq >> 16) & 0xffffu));
            x1h1 = bf2f((ushort)((xwq >> 32) & 0xffffu));
          }
        }
      } else if (role == 0){
        ld_frag16(hr, avm);
      } else if (role == 1){
        ld_frag32(xr_, hr, avx, avm);
      } else {
        int rb0 = slot * 16384 + b0i * 512 + uu;
        int rb1 = slot * 16384 + b1i * 512 + uu;
        const ushort* q0 = out0ring  + (rb0 & ~1);
        const ushort* q1 = pred0ring + (rb0 & ~1);
        const ushort* q2 = xw1ring + (size_t)((slot * 32 + b0i) * 512 + uu) * 4;
        const ushort* q3 = has1 ? (out0ring  + (rb1 & ~1)) : q0;
        const ushort* q4 = has1 ? (pred0ring + (rb1 & ~1)) : q1;
        const ushort* q5 = has1 ? (xw1ring + (size_t)((slot * 32 + b1i) * 512 + uu) * 4) : q2;
        unsigned int w0, w1, w3, w4; ull w2, w5;
        ld_frag32s(xr_, hr, q0, q1, q2, q3, q4, q5,
                   avx, avm, &w0, &w1, &w2, &w3, &w4, &w5);
        int hi = uu & 1;
        o_s0 = bf2f(hi ? (ushort)(w0 >> 16) : (ushort)(w0 & 0xffffu));
        p_s0 = bf2f(hi ? (ushort)(w1 >> 16) : (ushort)(w1 & 0xffffu));
        x1z0 = bf2f((ushort)(w2 & 0xffffu));
        x1r0 = bf2f((ushort)((w2 >> 16) & 0xffffu));
        x1h0 = bf2f((ushort)((w2 >> 32) & 0xffffu));
        if (has1){
          o_s1 = bf2f(hi ? (ushort)(w3 >> 16) : (ushort)(w3 & 0xffffu));
          p_s1 = bf2f(hi ? (ushort)(w4 >> 16) : (ushort)(w4 & 0xffffu));
          x1z1 = bf2f((ushort)(w5 & 0xffffu));
          x1r1 = bf2f((ushort)((w5 >> 16) & 0xffffu));
          x1h1 = bf2f((ushort)((w5 >> 32) & 0xffffu));
        }
      }

      f32x4 am0 = {0,0,0,0}, am1 = {0,0,0,0};
      if (role == 0){
        #pragma unroll
        for (int f = 0; f < 16; ++f){
          if (f & 1) am1 = MFMA16(avm[f], bfragR[f], am1);
          else       am0 = MFMA16(avm[f], bfragR[f], am0);
        }
        f32x4 am = am0 + am1;
        #pragma unroll
        for (int i = 0; i < 4; ++i)
          m_lds[gate][(mtile << 4) + (quad << 2) + i][lc] = am[i];
      } else {
        f32x4 ax0 = {0,0,0,0}, ax1 = {0,0,0,0};
        #pragma unroll
        for (int f = 0; f < 16; ++f){
          short8 bx = *(const short8*)(ks_lds + (((gate << 4) + f) << 9) + (lane << 3));
          short8 br = *(const short8*)(rs_lds + (((gate << 4) + f) << 9) + (lane << 3));
          if (f & 1){ am1 = MFMA16(avm[f], br, am1); ax1 = MFMA16(avx[f], bx, ax1); }
          else      { am0 = MFMA16(avm[f], br, am0); ax0 = MFMA16(avx[f], bx, ax0); }
        }
        f32x4 am = am0 + am1, ax = ax0 + ax1;
        #pragma unroll
        for (int i = 0; i < 4; ++i){
          m_lds[gate][(mtile << 4) + (quad << 2) + i][lc] = am[i];
          x_lds[gate][(mtile << 4) + (quad << 2) + i][lc] = ax[i];
        }
      }
    }
    __syncthreads();

    // ---- gate math; ring stores only (publish-early) ----
    ushort cb0 = 0, cb1 = 0;
    {
      int b = b0i;
      float mz = m_lds[0][b][u0] + bias_l[u0];
      float mr = m_lds[1][b][u0] + bias_l[16 + u0];
      float mh = m_lds[2][b][u0] + bias_l[32 + u0];
      float xz, xr, xh;
      if (role == 0){ xz = bf2f(xz0); xr = bf2f(xr0); xh = bf2f(xh0); }
      else if (role == 1){
        xz = x_lds[0][b][u0] + bias_l[48 + u0];
        xr = x_lds[1][b][u0] + bias_l[64 + u0];
        xh = x_lds[2][b][u0] + bias_l[80 + u0];
      } else {
        xz = x1z0 + a0 * x_lds[0][b][u0] + bias_l[48 + u0];
        xr = x1r0 + a0 * x_lds[1][b][u0] + bias_l[64 + u0];
        xh = x1h0 + a0 * x_lds[2][b][u0] + bias_l[80 + u0];
      }
      float z  = 1.f / (1.f + __expf(-(xz + mz)));
      float r  = 1.f / (1.f + __expf(-(xr + mr)));
      float axv = xh + r * mh;
      float hh = 1.f - 2.f / (1.f + __expf(2.f * axv));
      float hn = z * hp0 + (1.f - z) * hh;
      float hcv = hn + 0.1f * (hp0 - hn);
      hp0 = hcv;
      int rb = slot * 16384 + b * 512 + uu;
      st_hc2(h_ring + rb, f2bf(hcv));
      if (role == 0) st_hc2(out0ring + rb, f2bf(hn));
      else if (role == 1){
        st_hc2(pred0ring + rb, f2bf(hn));
        ull pv = (ull)f2bf(x_lds[0][b][u0])
               | ((ull)f2bf(x_lds[1][b][u0]) << 16)
               | ((ull)f2bf(x_lds[2][b][u0]) << 32);
        st_hc8(xw1ring + (size_t)((slot * 32 + b) * 512 + uu) * 4, pv);
      } else {
        cb0 = f2bf(o_s0 + a1 * p_s0 + a2 * hn);
      }
    }
    if (has1){
      int b = b1i;
      float mz = m_lds[0][b][u0] + bias_l[u0];
      float mr = m_lds[1][b][u0] + bias_l[16 + u0];
      float mh = m_lds[2][b][u0] + bias_l[32 + u0];
      float xz, xr, xh;
      if (role == 0){ xz = bf2f(xz1); xr = bf2f(xr1); xh = bf2f(xh1); }
      else if (role == 1){
        xz = x_lds[0][b][u0] + bias_l[48 + u0];
        xr = x_lds[1][b][u0] + bias_l[64 + u0];
        xh = x_lds[2][b][u0] + bias_l[80 + u0];
      } else {
        xz = x1z1 + a0 * x_lds[0][b][u0] + bias_l[48 + u0];
        xr = x1r1 + a0 * x_lds[1][b][u0] + bias_l[64 + u0];
        xh = x1h1 + a0 * x_lds[2][b][u0] + bias_l[80 + u0];
      }
      float z  = 1.f / (1.f + __expf(-(xz + mz)));
      float r  = 1.f / (1.f + __expf(-(xr + mr)));
      float axv = xh + r * mh;
      float hh = 1.f - 2.f / (1.f + __expf(2.f * axv));
      float hn = z * hp1 + (1.f - z) * hh;
      float hcv = hn + 0.1f * (hp1 - hn);
      hp1 = hcv;
      int rb = slot * 16384 + b * 512 + uu;
      st_hc2(h_ring + rb, f2bf(hcv));
      if (role == 0) st_hc2(out0ring + rb, f2bf(hn));
      else if (role == 1){
        st_hc2(pred0ring + rb, f2bf(hn));
        ull pv = (ull)f2bf(x_lds[0][b][u0])
               | ((ull)f2bf(x_lds[1][b][u0]) << 16)
               | ((ull)f2bf(x_lds[2][b][u0]) << 32);
        st_hc8(xw1ring + (size_t)((slot * 32 + b) * 512 + uu) * 4, pv);
      } else {
        cb1 = f2bf(o_s1 + a1 * p_s1 + a2 * hn);
      }
    }
    asm volatile("s_waitcnt vmcnt(0)" ::: "memory");  // ring stores at coherence pt
    __syncthreads();
    if (tid == 0)
      __hip_atomic_store(flags + (role * FSTEPS + s) * 32 + g, 1,
                         __ATOMIC_RELAXED, __HIP_MEMORY_SCOPE_AGENT);
    // role2 HBM output AFTER publish: off the critical path
    if (role == 2){
      comb[((size_t)b0i * 1024 + t) * 512 + uu] = cb0;
      if (has1) comb[((size_t)b1i * 1024 + t) * 512 + uu] = cb1;
    }

    if (role == 0){
      xz0 = nz0; xr0 = nr0; xh0 = nh0;
      xz1 = nz1; xr1 = nr1; xh1 = nh1;
    }
  }
}

// ---------------------------------------------------------------------------
extern "C" void kernel_launch(void* const* d_in, const int* in_sizes, int n_in,
                              void* d_out, int out_size, void* d_ws, size_t ws_size,
                              hipStream_t stream)
{
  const float* x   = (const float*)d_in[0];
  const float* k0  = (const float*)d_in[1];
  const float* r0  = (const float*)d_in[2];
  const float* b0  = (const float*)d_in[3];
  const float* ks  = (const float*)d_in[4];
  const float* rs  = (const float*)d_in[5];
  const float* bs  = (const float*)d_in[6];
  const float* h00 = (const float*)d_in[7];
  const float* h01 = (const float*)d_in[8];
  const float* h02 = (const float*)d_in[9];
  const float* a   = (const float*)d_in[10];
  const float* wd  = (const float*)d_in[11];
  const float* bd  = (const float*)d_in[12];
  float* outp = (float*)d_out;

  // ws layout (bytes), ~142.8 MB total:
  //   [0,        100663296)  XW0   [32768,1536] bf16
  //   [100663296,134217728)  comb  [32768,512] bf16 (first 16.8MB aliases x_bf)
  //   [134217728,136577024)  rings (2.25 MB)
  //   [136577024,136973312)  flags [3][1032][32] int
  //   [136973312,...]        bf16 weights k0b,r0b,ksb,rsb,wdb
  char* ws = (char*)d_ws;
  ushort* XW    = (ushort*)(ws);
  ushort* combp = (ushort*)(ws + 100663296u);
  ushort* xbf   = combp;                      // alias: dead before rec3_k runs
  ushort* rings = (ushort*)(ws + 134217728u);
  int*    flags = (int*)   (ws + 136577024u);
  ushort* k0b   = (ushort*)(ws + 136973312u);
  ushort* r0b   = (ushort*)(ws + 137759744u);
  ushort* ksb   = (ushort*)(ws + 139332608u);
  ushort* rsb   = (ushort*)(ws + 140905472u);
  ushort* wdb   = (ushort*)(ws + 142478336u);

  hipMemsetAsync(flags, 0, 3 * FSTEPS * 32 * sizeof(int), stream);

  dim3 blk(256);
  cvt_k<<<dim3(8192), blk, 0, stream>>>(x,  xbf, 8388608);
  cvt_k<<<dim3(384),  blk, 0, stream>>>(k0, k0b, 393216);
  cvt_k<<<dim3(768),  blk, 0, stream>>>(r0, r0b, 786432);
  cvt_k<<<dim3(768),  blk, 0, stream>>>(ks, ksb, 786432);
  cvt_k<<<dim3(768),  blk, 0, stream>>>(rs, rsb, 786432);
  cvt_k<<<dim3(128),  blk, 0, stream>>>(wd, wdb, 131072);

  // Layer-0 input projection (bulk GEMM)
  gemm_bias_k<0><<<dim3(512 * 24), blk, 0, stream>>>(xbf, k0b, b0, XW, 32768, 1536, 256);
  // Fused pipelined 3-layer recurrence (de-lockstepped, single-RT ring loads)
  rec3_k<<<dim3(NWG), dim3(384), 0, stream>>>(XW, r0b, ksb, rsb, b0, bs,
                                              h00, h01, h02, a, combp, rings, flags);
  // Final projection: comb @ wd + bd -> fp32 d_out
  gemm_bias_k<1><<<dim3(512 * 4), blk, 0, stream>>>(combp, wdb, bd, outp, 32768, 256, 512);
}